// Round 7
// baseline (443.020 us; speedup 1.0000x reference)
//
#include <hip/hip_runtime.h>
#include <hip/hip_bf16.h>
#include <math.h>

// Problem constants
#define BB 16
#define NN 3136
#define CC 384
#define HDS 8
#define DHH 48
#define AGG 49
#define HI 56
#define WI 56
#define OUTD 1000
#define SCALE_F 0.14433756729740643f  // 48^-0.5
#define QKVC 1152                     // q|k|v column stride

typedef __attribute__((ext_vector_type(8))) short short8;
typedef __attribute__((ext_vector_type(4))) float f32x4;

__device__ __forceinline__ float bf2f(unsigned short u) {
  union { unsigned u32; float f; } x;
  x.u32 = ((unsigned)u) << 16;
  return x.f;
}
__device__ __forceinline__ unsigned short f2bf(float f) {
  union { float f; unsigned u; } x;
  x.f = f;
  unsigned u = x.u;
  unsigned r = (u + 0x7fffu + ((u >> 16) & 1u)) >> 16;
  return (unsigned short)r;
}

// Fragment-pack offset functions (shared by producer & consumer).
__device__ __forceinline__ size_t xp_off(int gb, int ks, int j, int lane) {
  return ((((size_t)gb * 12 + ks) * 4 + j) * 64 + lane) * 8;
}
__device__ __forceinline__ size_t wp_off(int blk, int ks, int i, int lane) {
  return ((((size_t)blk * 12 + ks) * 4 + i) * 64 + lane) * 8;
}

// ---------------------------------------------------------------------------
// pack_x: x (fp32 [50176][384]) -> xp (bf16 fragment-packed). grid 784.
// ---------------------------------------------------------------------------
__global__ __launch_bounds__(256) void pack_x(const float* __restrict__ x,
                                              unsigned short* __restrict__ xp) {
  __shared__ unsigned short xlds[64 * 200];
  int gb = blockIdx.x;
  int tid = threadIdx.x;
  int lane = tid & 63, wv = tid >> 6;
  int lo = lane & 15, g = lane >> 4;
  int tok0 = gb * 64;

  for (int kh = 0; kh < 2; kh++) {
    if (kh) __syncthreads();
#pragma unroll
    for (int it = 0; it < 12; it++) {
      int idx = tid + it * 256;
      int tok = idx / 48, k4 = idx % 48;
      float4 f = *(const float4*)&x[(size_t)(tok0 + tok) * 384 + kh * 192 + k4 * 4];
      uint2 o;
      o.x = (unsigned)f2bf(f.x) | ((unsigned)f2bf(f.y) << 16);
      o.y = (unsigned)f2bf(f.z) | ((unsigned)f2bf(f.w) << 16);
      *(uint2*)&xlds[tok * 200 + k4 * 4] = o;
    }
    __syncthreads();
    for (int p = wv; p < 24; p += 4) {
      int ks = p >> 2, j = p & 3;
      uint4 v = *(const uint4*)&xlds[(j * 16 + lo) * 200 + ks * 32 + g * 8];
      *(uint4*)&xp[xp_off(gb, kh * 6 + ks, j, lane)] = v;
    }
  }
}

// ---------------------------------------------------------------------------
// pack_w: Wq (384x384) | Wkv (384x768) -> wp fragment-packed. grid 18.
// ---------------------------------------------------------------------------
__global__ __launch_bounds__(256) void pack_w(const float* __restrict__ Wq,
                                              const float* __restrict__ Wkv,
                                              unsigned short* __restrict__ wp) {
  __shared__ unsigned short wlds[64 * 392];
  int blk = blockIdx.x;
  int col0 = blk * 64;
  const float* src;
  int ncol, nloc;
  if (col0 < 384) { src = Wq; ncol = 384; nloc = col0; }
  else            { src = Wkv; ncol = 768; nloc = col0 - 384; }
  int tid = threadIdx.x;
  int lane = tid & 63, wv = tid >> 6;
  int lo = lane & 15, g = lane >> 4;

#pragma unroll
  for (int it = 0; it < 96; it++) {
    int idx = tid + it * 256;
    int k = idx >> 6, col = idx & 63;
    wlds[col * 392 + k] = f2bf(src[(size_t)k * ncol + nloc + col]);
  }
  __syncthreads();
  for (int p = wv; p < 48; p += 4) {
    int ks = p >> 2, i = p & 3;
    uint4 v = *(const uint4*)&wlds[(i * 16 + lo) * 392 + ks * 32 + g * 8];
    *(uint4*)&wp[wp_off(blk, ks, i, lane)] = v;
  }
}

// ---------------------------------------------------------------------------
// gemm_v3: qkv[50176][1152](bf16) = X @ W, fragment-direct (no LDS/barriers).
// ---------------------------------------------------------------------------
__global__ __launch_bounds__(256) void gemm_v3(const unsigned short* __restrict__ xp,
                                               const unsigned short* __restrict__ wp,
                                               unsigned short* __restrict__ Y) {
  const int tid = threadIdx.x;
  const int lane = tid & 63;
  const int wave = tid >> 6;
  const int lo = lane & 15, g = lane >> 4;
  const int wn2 = wave >> 1;
  const int wt2 = wave & 1;

  int wg = blockIdx.x;
  int l = (wg & 7) * 441 + (wg >> 3);
  int bx = l % 9, by = l / 9;
  const int col0 = bx * 128;
  const int row0 = by * 128;
  const int blkw = bx * 2 + wn2;
  const int gb = by * 2 + wt2;

  const unsigned short* wbase = wp + wp_off(blkw, 0, 0, lane);
  const unsigned short* xbase = xp + xp_off(gb, 0, 0, lane);

  f32x4 acc[4][4];
#pragma unroll
  for (int i = 0; i < 4; i++)
#pragma unroll
    for (int j = 0; j < 4; j++) acc[i][j] = (f32x4)0.f;

  short8 wfA[4], xfA[4], wfB[4], xfB[4];

  auto loadF = [&](short8* wf, short8* xf, int ks) {
    const unsigned short* wptr = wbase + (size_t)ks * 2048;
    const unsigned short* xptr = xbase + (size_t)ks * 2048;
#pragma unroll
    for (int i = 0; i < 4; i++) wf[i] = *(const short8*)(wptr + i * 512);
#pragma unroll
    for (int j = 0; j < 4; j++) xf[j] = *(const short8*)(xptr + j * 512);
  };
  auto mfmaF = [&](short8* wf, short8* xf) {
#pragma unroll
    for (int i = 0; i < 4; i++)
#pragma unroll
      for (int j = 0; j < 4; j++)
        acc[i][j] = __builtin_amdgcn_mfma_f32_16x16x32_bf16(wf[i], xf[j], acc[i][j], 0, 0, 0);
  };

  loadF(wfA, xfA, 0);
#pragma unroll
  for (int kp = 0; kp < 6; kp++) {
    loadF(wfB, xfB, 2 * kp + 1);
    mfmaF(wfA, xfA);
    if (kp < 5) loadF(wfA, xfA, 2 * kp + 2);
    mfmaF(wfB, xfB);
  }

#pragma unroll
  for (int j = 0; j < 4; j++) {
    int token = row0 + wt2 * 64 + j * 16 + lo;
#pragma unroll
    for (int i = 0; i < 4; i++) {
      int ncol = col0 + wn2 * 64 + i * 16 + g * 4;
      uint2 o;
      o.x = (unsigned)f2bf(acc[i][j][0]) | ((unsigned)f2bf(acc[i][j][1]) << 16);
      o.y = (unsigned)f2bf(acc[i][j][2]) | ((unsigned)f2bf(acc[i][j][3]) << 16);
      *(uint2*)&Y[(size_t)token * QKVC + ncol] = o;
    }
  }
}

// ---------------------------------------------------------------------------
// Combined bias precompute
// ---------------------------------------------------------------------------
__global__ __launch_bounds__(256) void make_cbias(
    const float* __restrict__ na, const float* __restrict__ ha,
    const float* __restrict__ wa, const float* __restrict__ an,
    const float* __restrict__ ah, const float* __restrict__ aw,
    float* __restrict__ cb1, float* __restrict__ cb2) {
  int ha_idx = blockIdx.x;
  int h = ha_idx / AGG, a = ha_idx % AGG;
  for (int n = threadIdx.x; n < NN; n += 256) {
    int r = n / WI, c = n % WI;
    size_t base = (size_t)ha_idx * NN + n;
    cb1[base] = na[base] + ha[(h * HI + r) * AGG + a] + wa[(h * WI + c) * AGG + a];
    cb2[base] = an[base] + ah[(size_t)ha_idx * HI + r] + aw[(size_t)ha_idx * WI + c];
  }
}

// ---------------------------------------------------------------------------
// agent = pool(q) over 8x8 blocks -> bf16
// ---------------------------------------------------------------------------
__global__ __launch_bounds__(384) void pool_agent(const unsigned short* __restrict__ qkv,
                                                  unsigned short* __restrict__ agbf) {
  int blk = blockIdx.x;
  int b = blk / AGG, a = blk % AGG;
  int p1 = a / 7, p2 = a % 7;
  int c = threadIdx.x;
  float s = 0.f;
#pragma unroll
  for (int i = 0; i < 8; i++)
#pragma unroll
    for (int j = 0; j < 8; j++) {
      int n = (p1 * 8 + i) * WI + (p2 * 8 + j);
      s += bf2f(qkv[((size_t)b * NN + n) * QKVC + c]);
    }
  agbf[(size_t)blk * CC + c] = f2bf(s * (1.f / 64.f));
}

// ---------------------------------------------------------------------------
// Agent attention, persistent per (b,h,quarter). 256 thr = 4 waves.
// ---------------------------------------------------------------------------
__global__ __launch_bounds__(256) void agent_attn_v2(
    const unsigned short* __restrict__ qkv, const unsigned short* __restrict__ agbf,
    const float* __restrict__ cb2, float* __restrict__ laccg,
    float* __restrict__ avacc) {
  int z = blockIdx.x;
  int qtr = z & 3;
  int h = (z >> 2) & 7;
  int b = z >> 5;
  int tid = threadIdx.x, lane = tid & 63, wv = tid >> 6;
  int lo = lane & 15, g = lane >> 4;

  __shared__ __align__(16) unsigned short vT[4][48 * 72];
  __shared__ __align__(16) unsigned short pT[4][64 * 72];
  __shared__ float ldsAV[AGG * 48];
  __shared__ float ldsL[AGG];

  for (int i = tid; i < AGG * 48; i += 256) ldsAV[i] = 0.f;
  if (tid < AGG) ldsL[tid] = 0.f;
  __syncthreads();

  short8 af0[4], af1[4];
#pragma unroll
  for (int mt = 0; mt < 4; mt++) {
    int a = mt * 16 + lo;
    int ac = a < AGG ? a : AGG - 1;
    const unsigned short* p = agbf + ((size_t)b * AGG + ac) * CC + h * 48;
    af0[mt] = *(const short8*)(p + g * 8);
    if (g < 2) af1[mt] = *(const short8*)(p + 32 + g * 8);
    else { short8 zz = {0, 0, 0, 0, 0, 0, 0, 0}; af1[mt] = zz; }
  }

  f32x4 acc2[4][3];
#pragma unroll
  for (int mt = 0; mt < 4; mt++)
#pragma unroll
    for (int ntd = 0; ntd < 3; ntd++) acc2[mt][ntd] = (f32x4)0.f;
  float laccR[4][4];
#pragma unroll
  for (int mt = 0; mt < 4; mt++)
#pragma unroll
    for (int r = 0; r < 4; r++) laccR[mt][r] = 0.f;

  const int tok0 = qtr * 784;
  for (int ci = 0; ci < 4; ci++) {
    const int vcnt = (ci < 3) ? 256 : 16;
    const int tb = tok0 + ci * 256;
    const int wb = tb + wv * 64;

    {
      int t = lane;
      int n = wb + t;
      int nc = n < NN ? n : NN - 1;
      const unsigned short* vp = qkv + ((size_t)b * NN + nc) * QKVC + 768 + h * 48;
#pragma unroll
      for (int c8 = 0; c8 < 6; c8++) {
        short8 s8 = *(const short8*)(vp + c8 * 8);
#pragma unroll
        for (int e = 0; e < 8; e++) vT[wv][(c8 * 8 + e) * 72 + t] = (unsigned short)s8[e];
      }
    }

    short8 kf0[4], kf1[4];
#pragma unroll
    for (int nt = 0; nt < 4; nt++) {
      int n = wb + nt * 16 + lo;
      int nc = n < NN ? n : NN - 1;
      const unsigned short* kp = qkv + ((size_t)b * NN + nc) * QKVC + 384 + h * 48;
      kf0[nt] = *(const short8*)(kp + g * 8);
      if (g < 2) kf1[nt] = *(const short8*)(kp + 32 + g * 8);
      else { short8 zz = {0, 0, 0, 0, 0, 0, 0, 0}; kf1[nt] = zz; }
    }

    f32x4 acc[4][4];
#pragma unroll
    for (int mt = 0; mt < 4; mt++)
#pragma unroll
      for (int nt = 0; nt < 4; nt++) acc[mt][nt] = (f32x4)0.f;
#pragma unroll
    for (int mt = 0; mt < 4; mt++)
#pragma unroll
      for (int nt = 0; nt < 4; nt++) {
        acc[mt][nt] = __builtin_amdgcn_mfma_f32_16x16x32_bf16(af0[mt], kf0[nt], acc[mt][nt], 0, 0, 0);
        acc[mt][nt] = __builtin_amdgcn_mfma_f32_16x16x32_bf16(af1[mt], kf1[nt], acc[mt][nt], 0, 0, 0);
      }

#pragma unroll
    for (int mt = 0; mt < 4; mt++)
#pragma unroll
      for (int nt = 0; nt < 4; nt++)
#pragma unroll
        for (int r = 0; r < 4; r++) {
          int a = mt * 16 + g * 4 + r;
          int tl = wv * 64 + nt * 16 + lo;
          float e = 0.f;
          if (a < AGG && tl < vcnt)
            e = __expf(acc[mt][nt][r] * SCALE_F + cb2[((size_t)h * AGG + a) * NN + tb + tl]);
          acc[mt][nt][r] = e;
        }

#pragma unroll
    for (int mt = 0; mt < 4; mt++)
#pragma unroll
      for (int r = 0; r < 4; r++)
        laccR[mt][r] += acc[mt][0][r] + acc[mt][1][r] + acc[mt][2][r] + acc[mt][3][r];

#pragma unroll
    for (int mt = 0; mt < 4; mt++)
#pragma unroll
      for (int nt = 0; nt < 4; nt++)
#pragma unroll
        for (int r = 0; r < 4; r++) {
          int a = mt * 16 + g * 4 + r;
          int t = nt * 16 + lo;
          pT[wv][a * 72 + t] = f2bf(acc[mt][nt][r]);
        }

    short8 pa0[4], pa1[4], vb0[3], vb1[3];
#pragma unroll
    for (int mt = 0; mt < 4; mt++) {
      const unsigned short* p = &pT[wv][(mt * 16 + lo) * 72 + g * 8];
      pa0[mt] = *(const short8*)p;
      pa1[mt] = *(const short8*)(p + 32);
    }
#pragma unroll
    for (int ntd = 0; ntd < 3; ntd++) {
      const unsigned short* p = &vT[wv][(ntd * 16 + lo) * 72 + g * 8];
      vb0[ntd] = *(const short8*)p;
      vb1[ntd] = *(const short8*)(p + 32);
    }
#pragma unroll
    for (int mt = 0; mt < 4; mt++)
#pragma unroll
      for (int ntd = 0; ntd < 3; ntd++) {
        acc2[mt][ntd] = __builtin_amdgcn_mfma_f32_16x16x32_bf16(pa0[mt], vb0[ntd], acc2[mt][ntd], 0, 0, 0);
        acc2[mt][ntd] = __builtin_amdgcn_mfma_f32_16x16x32_bf16(pa1[mt], vb1[ntd], acc2[mt][ntd], 0, 0, 0);
      }
  }

#pragma unroll
  for (int mt = 0; mt < 4; mt++)
#pragma unroll
    for (int r = 0; r < 4; r++) {
      float s = laccR[mt][r];
      s += __shfl_xor(s, 1); s += __shfl_xor(s, 2);
      s += __shfl_xor(s, 4); s += __shfl_xor(s, 8);
      if (lo == 0) {
        int a = mt * 16 + g * 4 + r;
        if (a < AGG) atomicAdd(&ldsL[a], s);
      }
    }
#pragma unroll
  for (int mt = 0; mt < 4; mt++)
#pragma unroll
    for (int ntd = 0; ntd < 3; ntd++)
#pragma unroll
      for (int r = 0; r < 4; r++) {
        int a = mt * 16 + g * 4 + r;
        if (a < AGG) atomicAdd(&ldsAV[a * 48 + ntd * 16 + lo], acc2[mt][ntd][r]);
      }
  __syncthreads();
  size_t obase = ((size_t)b * HDS + h) * AGG;
  for (int i = tid; i < AGG * 48; i += 256) atomicAdd(&avacc[obase * 48 + i], ldsAV[i]);
  if (tid < AGG) atomicAdd(&laccg[obase + tid], ldsL[tid]);
}

// ---------------------------------------------------------------------------
// Normalize: av = avacc / l
// ---------------------------------------------------------------------------
__global__ __launch_bounds__(64) void av_normalize(const float* __restrict__ laccg,
                                                   const float* __restrict__ avacc,
                                                   float* __restrict__ av) {
  int blk = blockIdx.x;
  int d = threadIdx.x;
  if (d < 48) av[(size_t)blk * 48 + d] = avacc[(size_t)blk * 48 + d] / laccg[blk];
}

// ---------------------------------------------------------------------------
// q-attention, persistent per (b,h,quarter).
// ---------------------------------------------------------------------------
__global__ __launch_bounds__(256) void q_attn_v2(
    const unsigned short* __restrict__ qkv, const unsigned short* __restrict__ agbf,
    const float* __restrict__ av, const float* __restrict__ cb1,
    float* __restrict__ accb) {
  int z = blockIdx.x;
  int qtr = z & 3;
  int h = (z >> 2) & 7;
  int b = z >> 5;
  int tid = threadIdx.x, lane = tid & 63, wv = tid >> 6;
  int lo = lane & 15, g = lane >> 4;

  __shared__ __align__(16) unsigned short avT[48 * 72];
  __shared__ __align__(16) unsigned short pT[4][64 * 72];

  for (int i = tid; i < (48 * 72) / 2; i += 256) ((unsigned*)avT)[i] = 0;
  __syncthreads();
  for (int idx = tid; idx < AGG * 48; idx += 256) {
    int a = idx / 48, d = idx % 48;
    avT[d * 72 + a] = f2bf(av[(((size_t)b * HDS + h) * AGG + a) * 48 + d]);
  }
  __syncthreads();

  short8 af0[4], af1[4];
#pragma unroll
  for (int mt = 0; mt < 4; mt++) {
    int a = mt * 16 + lo;
    int ac = a < AGG ? a : AGG - 1;
    const unsigned short* p = agbf + ((size_t)b * AGG + ac) * CC + h * 48;
    af0[mt] = *(const short8*)(p + g * 8);
    if (g < 2) af1[mt] = *(const short8*)(p + 32 + g * 8);
    else { short8 zz = {0, 0, 0, 0, 0, 0, 0, 0}; af1[mt] = zz; }
  }
  short8 vf0[3], vf1[3];
#pragma unroll
  for (int mtd = 0; mtd < 3; mtd++) {
    const unsigned short* p = &avT[(mtd * 16 + lo) * 72 + g * 8];
    vf0[mtd] = *(const short8*)p;
    vf1[mtd] = *(const short8*)(p + 32);
  }

  f32x4 acc2[3][4];
#pragma unroll
  for (int mtd = 0; mtd < 3; mtd++)
#pragma unroll
    for (int nt = 0; nt < 4; nt++) acc2[mtd][nt] = (f32x4)0.f;

  const int tok0 = qtr * 784;
  for (int ci = 0; ci < 4; ci++) {
    const int vcnt = (ci < 3) ? 256 : 16;
    const int tb = tok0 + ci * 256;
    const int wb = tb + wv * 64;

    short8 qf0[4], qf1[4];
#pragma unroll
    for (int nt = 0; nt < 4; nt++) {
      int n = wb + nt * 16 + lo;
      int nc = n < NN ? n : NN - 1;
      const unsigned short* qp = qkv + ((size_t)b * NN + nc) * QKVC + h * 48;
      qf0[nt] = *(const short8*)(qp + g * 8);
      if (g < 2) qf1[nt] = *(const short8*)(qp + 32 + g * 8);
      else { short8 zz = {0, 0, 0, 0, 0, 0, 0, 0}; qf1[nt] = zz; }
    }
    f32x4 acc[4][4];
#pragma unroll
    for (int mt = 0; mt < 4; mt++)
#pragma unroll
      for (int nt = 0; nt < 4; nt++) acc[mt][nt] = (f32x4)0.f;
#pragma unroll
    for (int mt = 0; mt < 4; mt++)
#pragma unroll
      for (int nt = 0; nt < 4; nt++) {
        acc[mt][nt] = __builtin_amdgcn_mfma_f32_16x16x32_bf16(af0[mt], qf0[nt], acc[mt][nt], 0, 0, 0);
        acc[mt][nt] = __builtin_amdgcn_mfma_f32_16x16x32_bf16(af1[mt], qf1[nt], acc[mt][nt], 0, 0, 0);
      }

#pragma unroll
    for (int nt = 0; nt < 4; nt++) {
      int tlc = wv * 64 + nt * 16 + lo;
      int n = tb + tlc;
      int nc = n < NN ? n : NN - 1;
      float lsum = 0.f;
#pragma unroll
      for (int mt = 0; mt < 4; mt++)
#pragma unroll
        for (int r = 0; r < 4; r++) {
          int a = mt * 16 + g * 4 + r;
          float e = 0.f;
          if (a < AGG)
            e = __expf(acc[mt][nt][r] * SCALE_F + cb1[((size_t)h * AGG + a) * NN + nc]);
          acc[mt][nt][r] = e;
          lsum += e;
        }
      lsum += __shfl_xor(lsum, 16);
      lsum += __shfl_xor(lsum, 32);
      float inv = (tlc < vcnt) ? 1.f / lsum : 0.f;
      int t = nt * 16 + lo;
#pragma unroll
      for (int mt = 0; mt < 4; mt++)
#pragma unroll
        for (int rp = 0; rp < 2; rp++) {
          unsigned u0 = f2bf(acc[mt][nt][rp * 2] * inv);
          unsigned u1 = f2bf(acc[mt][nt][rp * 2 + 1] * inv);
          int a = mt * 16 + g * 4 + rp * 2;
          *(unsigned*)&pT[wv][t * 72 + a] = u0 | (u1 << 16);
        }
    }

    short8 pf0[4], pf1[4];
#pragma unroll
    for (int nt = 0; nt < 4; nt++) {
      const unsigned short* p = &pT[wv][(nt * 16 + lo) * 72 + g * 8];
      pf0[nt] = *(const short8*)p;
      pf1[nt] = *(const short8*)(p + 32);
    }
#pragma unroll
    for (int mtd = 0; mtd < 3; mtd++)
#pragma unroll
      for (int nt = 0; nt < 4; nt++) {
        acc2[mtd][nt] = __builtin_amdgcn_mfma_f32_16x16x32_bf16(vf0[mtd], pf0[nt], acc2[mtd][nt], 0, 0, 0);
        acc2[mtd][nt] = __builtin_amdgcn_mfma_f32_16x16x32_bf16(vf1[mtd], pf1[nt], acc2[mtd][nt], 0, 0, 0);
      }
  }

#pragma unroll
  for (int mtd = 0; mtd < 3; mtd++)
#pragma unroll
    for (int r = 0; r < 4; r++) {
      float v = acc2[mtd][0][r] + acc2[mtd][1][r] + acc2[mtd][2][r] + acc2[mtd][3][r];
      v += __shfl_xor(v, 1); v += __shfl_xor(v, 2);
      v += __shfl_xor(v, 4); v += __shfl_xor(v, 8);
      if (lo == 0) {
        int d = mtd * 16 + g * 4 + r;
        atomicAdd(&accb[(size_t)b * CC + h * 48 + d], v);
      }
    }
}

// ---------------------------------------------------------------------------
// dwc via border-sum algebra: pass 1 — per-row sums + edge cols of v
// ---------------------------------------------------------------------------
__global__ __launch_bounds__(384) void dwc_rows(const unsigned short* __restrict__ qkv,
                                                float* __restrict__ rowsum,
                                                float* __restrict__ edge0,
                                                float* __restrict__ edge1) {
  int z = blockIdx.x;
  int b = z / HI, r = z % HI;
  int c = threadIdx.x;
  const unsigned short* base = qkv + ((size_t)b * NN + (size_t)r * WI) * QKVC + 768 + c;
  float s = 0.f, e0 = 0.f, e1 = 0.f;
  for (int w = 0; w < WI; w++) {
    float v = bf2f(base[(size_t)w * QKVC]);
    s += v;
    if (w == 0) e0 = v;
    if (w == WI - 1) e1 = v;
  }
  rowsum[(size_t)z * CC + c] = s;
  edge0[(size_t)z * CC + c] = e0;
  edge1[(size_t)z * CC + c] = e1;
}

// pass 2 — combine
__global__ __launch_bounds__(384) void dwc_combine(const float* __restrict__ rowsum,
                                                   const float* __restrict__ edge0,
                                                   const float* __restrict__ edge1,
                                                   const float* __restrict__ w,
                                                   float* __restrict__ accb) {
  int b = blockIdx.x;
  int c = threadIdx.x;
  float T = 0.f, C0 = 0.f, C55 = 0.f;
  float R0 = 0.f, R55 = 0.f, v00 = 0.f, v0W = 0.f, vH0 = 0.f, vHW = 0.f;
  for (int r = 0; r < HI; r++) {
    size_t idx = ((size_t)(b * HI + r)) * CC + c;
    float rs = rowsum[idx], a0 = edge0[idx], a1 = edge1[idx];
    T += rs; C0 += a0; C55 += a1;
    if (r == 0) { R0 = rs; v00 = a0; v0W = a1; }
    if (r == HI - 1) { R55 = rs; vH0 = a0; vHW = a1; }
  }
  float acc = 0.f;
#pragma unroll
  for (int i = 0; i < 3; i++) {
    int di = i - 1;
#pragma unroll
    for (int j = 0; j < 3; j++) {
      int dj = j - 1;
      float S = T;
      if (di == 1) S -= R0; else if (di == -1) S -= R55;
      if (dj == 1) S -= C0; else if (dj == -1) S -= C55;
      if (di != 0 && dj != 0)
        S += (di == 1) ? ((dj == 1) ? v00 : v0W) : ((dj == 1) ? vH0 : vHW);
      acc += w[c * 9 + i * 3 + j] * S;
    }
  }
  atomicAdd(&accb[(size_t)b * CC + c], acc);
}

// ---------------------------------------------------------------------------
// Head, wave-parallel GEMVs.
// head_proj: pj[b][o] = dot(pre[b], Wproj[:,o]) + bproj[o]
// 96 waves: w = b*6 + oc. grid 24 x 256.
// ---------------------------------------------------------------------------
__global__ __launch_bounds__(256) void head_proj(
    const float* __restrict__ accb, const float* __restrict__ dwc_b,
    const float* __restrict__ Wproj, const float* __restrict__ bproj,
    float* __restrict__ pj) {
  int w = blockIdx.x * 4 + (threadIdx.x >> 6);
  int lane = threadIdx.x & 63;
  int b = w / 6, oc = w % 6;
  int o = oc * 64 + lane;
  const float* ab = accb + (size_t)b * CC;
  float s = 0.f;
#pragma unroll 4
  for (int k = 0; k < CC; k++) {
    float pk = ab[k] * (1.f / (float)NN) + dwc_b[k];
    s += pk * Wproj[(size_t)k * CC + o];
  }
  pj[(size_t)b * CC + o] = s + bproj[o];
}

// head_ln: LN over pj rows -> h0. grid 16 x 384.
__global__ __launch_bounds__(384) void head_ln(const float* __restrict__ pj,
                                               const float* __restrict__ ln_g,
                                               const float* __restrict__ ln_b,
                                               float* __restrict__ h0) {
  int b = blockIdx.x;
  int tid = threadIdx.x;
  __shared__ float red[8];
  float v = pj[(size_t)b * CC + tid];
  float m;
  {
    float s = v;
#pragma unroll
    for (int o = 32; o > 0; o >>= 1) s += __shfl_down(s, o);
    if ((tid & 63) == 0) red[tid >> 6] = s;
    __syncthreads();
    if (tid == 0) {
      float t = 0.f;
      for (int i = 0; i < 6; i++) t += red[i];
      red[6] = t * (1.f / (float)CC);
    }
    __syncthreads();
    m = red[6];
  }
  float dv = v - m;
  __syncthreads();
  float var;
  {
    float s = dv * dv;
#pragma unroll
    for (int o = 32; o > 0; o >>= 1) s += __shfl_down(s, o);
    if ((tid & 63) == 0) red[tid >> 6] = s;
    __syncthreads();
    if (tid == 0) {
      float t = 0.f;
      for (int i = 0; i < 6; i++) t += red[i];
      red[7] = t * (1.f / (float)CC);
    }
    __syncthreads();
    var = red[7];
  }
  h0[(size_t)b * CC + tid] = dv * rsqrtf(var + 1e-5f) * ln_g[tid] + ln_b[tid];
}

// head_mlp1: h1[b][o] = gelu(dot(h0[b], W1[:,o]) + b1[o]); 192 waves, grid 48.
__global__ __launch_bounds__(256) void head_mlp1(const float* __restrict__ h0,
                                                 const float* __restrict__ W1,
                                                 const float* __restrict__ b1,
                                                 float* __restrict__ h1) {
  int w = blockIdx.x * 4 + (threadIdx.x >> 6);
  int lane = threadIdx.x & 63;
  int b = w / 12, oc = w % 12;
  int o = oc * 64 + lane;
  const float* hb = h0 + (size_t)b * CC;
  float s = 0.f;
#pragma unroll 4
  for (int k = 0; k < CC; k++) s += hb[k] * W1[(size_t)k * (2 * CC) + o];
  s += b1[o];
  h1[(size_t)b * (2 * CC) + o] = 0.5f * s * (1.f + erff(s * 0.70710678118654752f));
}

// head_mlp2: out[b][o] = dot(h1[b], W2[:,o]) + b2[o]; 256 waves, grid 64.
__global__ __launch_bounds__(256) void head_mlp2(const float* __restrict__ h1,
                                                 const float* __restrict__ W2,
                                                 const float* __restrict__ b2,
                                                 float* __restrict__ out) {
  int w = blockIdx.x * 4 + (threadIdx.x >> 6);
  int lane = threadIdx.x & 63;
  int b = w / 16, oc = w % 16;
  int o = oc * 64 + lane;
  bool valid = o < OUTD;
  int oc2 = valid ? o : OUTD - 1;
  const float* hb = h1 + (size_t)b * (2 * CC);
  float s = 0.f;
#pragma unroll 4
  for (int k = 0; k < 2 * CC; k++) s += hb[k] * W2[(size_t)k * OUTD + oc2];
  if (valid) out[(size_t)b * OUTD + o] = s + b2[o];
}

// ---------------------------------------------------------------------------
extern "C" void kernel_launch(void* const* d_in, const int* in_sizes, int n_in,
                              void* d_out, int out_size, void* d_ws,
                              size_t ws_size, hipStream_t stream) {
  const float* x = (const float*)d_in[0];
  const float* Wq = (const float*)d_in[1];
  const float* Wkv = (const float*)d_in[2];
  const float* an_bias = (const float*)d_in[3];
  const float* na_bias = (const float*)d_in[4];
  const float* ah_bias = (const float*)d_in[5];
  const float* aw_bias = (const float*)d_in[6];
  const float* ha_bias = (const float*)d_in[7];
  const float* wa_bias = (const float*)d_in[8];
  const float* dwc_w = (const float*)d_in[9];
  const float* dwc_b = (const float*)d_in[10];
  const float* Wproj = (const float*)d_in[11];
  const float* bproj = (const float*)d_in[12];
  const float* ln_g = (const float*)d_in[13];
  const float* ln_b = (const float*)d_in[14];
  const float* W1 = (const float*)d_in[15];
  const float* b1 = (const float*)d_in[16];
  const float* W2 = (const float*)d_in[17];
  const float* b2 = (const float*)d_in[18];
  float* out = (float*)d_out;

  const size_t M = (size_t)BB * NN;  // 50176
  char* wsp = (char*)d_ws;
  unsigned short* xp = (unsigned short*)wsp;   wsp += M * CC * 2;
  unsigned short* wpb = (unsigned short*)wsp;  wsp += (size_t)QKVC * CC * 2;
  unsigned short* qkv = (unsigned short*)wsp;  wsp += M * QKVC * 2;
  unsigned short* agbf = (unsigned short*)wsp; wsp += (size_t)784 * CC * 2;
  float* cb1 = (float*)wsp;                    wsp += (size_t)HDS * AGG * NN * 4;
  float* cb2 = (float*)wsp;                    wsp += (size_t)HDS * AGG * NN * 4;
  float* laccg = (float*)wsp;                  wsp += (size_t)BB * HDS * AGG * 4;
  float* avacc = (float*)wsp;                  wsp += (size_t)BB * HDS * AGG * 48 * 4;
  float* av = (float*)wsp;                     wsp += (size_t)BB * HDS * AGG * 48 * 4;
  float* accb = (float*)wsp;                   wsp += (size_t)BB * CC * 4;
  float* rowsum = (float*)wsp;                 wsp += (size_t)BB * HI * CC * 4;
  float* edge0 = (float*)wsp;                  wsp += (size_t)BB * HI * CC * 4;
  float* edge1 = (float*)wsp;                  wsp += (size_t)BB * HI * CC * 4;
  float* pj = (float*)wsp;                     wsp += (size_t)BB * CC * 4;
  float* h0b = (float*)wsp;                    wsp += (size_t)BB * CC * 4;
  float* h1b = (float*)wsp;                    wsp += (size_t)BB * 2 * CC * 4;

  hipMemsetAsync(accb, 0, (size_t)BB * CC * sizeof(float), stream);
  hipMemsetAsync(laccg, 0, (size_t)BB * HDS * AGG * sizeof(float), stream);
  hipMemsetAsync(avacc, 0, (size_t)BB * HDS * AGG * 48 * sizeof(float), stream);

  dim3 blk256(256);
  hipLaunchKernelGGL(pack_x, dim3(784), blk256, 0, stream, x, xp);
  hipLaunchKernelGGL(pack_w, dim3(18), blk256, 0, stream, Wq, Wkv, wpb);
  hipLaunchKernelGGL(make_cbias, dim3(HDS * AGG), blk256, 0, stream, na_bias,
                     ha_bias, wa_bias, an_bias, ah_bias, aw_bias, cb1, cb2);
  hipLaunchKernelGGL(gemm_v3, dim3(3528), blk256, 0, stream, xp, wpb, qkv);
  hipLaunchKernelGGL(pool_agent, dim3(BB * AGG), dim3(384), 0, stream, qkv, agbf);
  hipLaunchKernelGGL(agent_attn_v2, dim3(BB * HDS * 4), blk256, 0, stream,
                     qkv, agbf, cb2, laccg, avacc);
  hipLaunchKernelGGL(av_normalize, dim3(BB * HDS * AGG), dim3(64), 0, stream,
                     laccg, avacc, av);
  hipLaunchKernelGGL(q_attn_v2, dim3(BB * HDS * 4), blk256, 0, stream, qkv,
                     agbf, av, cb1, accb);
  hipLaunchKernelGGL(dwc_rows, dim3(BB * HI), dim3(384), 0, stream, qkv, rowsum, edge0, edge1);
  hipLaunchKernelGGL(dwc_combine, dim3(BB), dim3(384), 0, stream, rowsum, edge0,
                     edge1, dwc_w, accb);
  hipLaunchKernelGGL(head_proj, dim3(24), blk256, 0, stream, accb, dwc_b, Wproj,
                     bproj, pj);
  hipLaunchKernelGGL(head_ln, dim3(BB), dim3(384), 0, stream, pj, ln_g, ln_b, h0b);
  hipLaunchKernelGGL(head_mlp1, dim3(48), blk256, 0, stream, h0b, W1, b1, h1b);
  hipLaunchKernelGGL(head_mlp2, dim3(64), blk256, 0, stream, h1b, W2, b2, out);
}